// Round 3
// baseline (290.148 us; speedup 1.0000x reference)
//
#include <hip/hip_runtime.h>
#include <hip/hip_bf16.h>

typedef short bh8 __attribute__((ext_vector_type(8)));
typedef float f4 __attribute__((ext_vector_type(4)));
typedef unsigned short u16x8 __attribute__((ext_vector_type(8)));
typedef unsigned short u16x4 __attribute__((ext_vector_type(4)));

#define N_TOK 2048
#define BATCH 8
#define DIM   1024

// f32 -> bf16 round-to-nearest-even (finite values only)
static __device__ __forceinline__ unsigned short f2bf(float f) {
  unsigned int b = __float_as_uint(f);
  b += 0x7FFFu + ((b >> 16) & 1u);
  return (unsigned short)(b >> 16);
}

static __device__ __forceinline__ void gld16(const void* g, void* lds) {
  __builtin_amdgcn_global_load_lds(
      (const __attribute__((address_space(1))) unsigned int*)g,
      (__attribute__((address_space(3))) unsigned int*)lds, 16, 0, 0);
}

// Stage a [128 rows x 64 k] bf16 half-tile into a 16 KB LDS region with 512
// threads (2 x gld16 each).  Linear LDS dest, XOR-swizzled per-lane global
// source (G21): LDS[row*128 + (kb ^ ((row&7)<<4))] = G[row][kb].
static __device__ __forceinline__ void stage_half(const unsigned char* g, size_t ldb,
                                                  unsigned char* ldsreg, int w, int l) {
  const int rgrp = l >> 3;                       // row within 8-row granule
  const int srcb = (((l & 7) ^ rgrp) << 4);      // swizzled byte offset in row
  gld16(g + (size_t)(w * 8 + rgrp) * ldb + srcb, ldsreg + w * 1024);
  gld16(g + (size_t)((w + 8) * 8 + rgrp) * ldb + srcb, ldsreg + (w + 8) * 1024);
}

// read one 16x16x32 fragment (8 consecutive k at one row), swizzle-aware
static __device__ __forceinline__ bh8 fragld(const unsigned char* lds, int row, int kbyte) {
  return *(const bh8*)(lds + row * 128 + (kbyte ^ ((row & 7) << 4)));
}

// ---- 8-phase 256x256 K-loop core (T2+T3+T4+T5).  acc[8][4], waves 2M x 4N. ----
// Schedule per K-tile t (buffers alternate t&1; regions 0=A0 1=A1 2=B0 3=B1):
//   ph0: read B frags (8 ds_read) + A frags p=0 (4), stage A0(t+1)
//   ph1: A frags p=1, stage A1(t+1)
//   ph2: A frags p=2, stage B0(t+2)
//   ph3: A frags p=3, stage B1(t+2), s_waitcnt vmcnt(4)
// each phase: barrier; lgkmcnt(0); setprio(1); 16 MFMA; setprio(0); barrier.
// Every stage-issue is barrier-separated from the staged region's last read.
static __device__ __forceinline__ void gemm8_core(unsigned char* lds,
    const unsigned char* Ab, size_t lda, const unsigned char* Bb, size_t ldb,
    int nk, int w, int l, f4 acc[8][4]) {
  const int wm = w >> 2, wn = w & 3;
  auto SH = [&](int part, int src, int dbuf) {
    const unsigned char* g = (part < 2 ? Ab + (size_t)(part * 128) * lda
                                       : Bb + (size_t)((part - 2) * 128) * ldb)
                             + (size_t)src * 128;
    stage_half(g, part < 2 ? lda : ldb, lds + dbuf * 65536 + part * 16384, w, l);
  };

  // prologue: tile0 (all 4 halves) + tile1 B halves; wait tile0 resident
  SH(0, 0, 0); SH(1, 0, 0); SH(2, 0, 0); SH(3, 0, 0); SH(2, 1, 1); SH(3, 1, 1);
  asm volatile("s_waitcnt vmcnt(4)" ::: "memory");
  __builtin_amdgcn_s_barrier();

  for (int t = 0; t < nk; ++t) {
    unsigned char* base = lds + (t & 1) * 65536;
    const unsigned char* myA = base + wm * 16384;
    const unsigned char* myB = base + 32768 + (wn >> 1) * 16384;
    const int brow = (wn & 1) * 64;
    const int t1 = (t + 1 < nk) ? t + 1 : t;   // clamped dummy keeps vmcnt uniform;
    const int t2 = (t + 2 < nk) ? t + 2 : t;   // dummy targets are dead regions
    bh8 bfr[4][2];
    #pragma unroll
    for (int p = 0; p < 4; ++p) {
      if (p == 0) {
        #pragma unroll
        for (int j = 0; j < 4; ++j)
          #pragma unroll
          for (int ks = 0; ks < 2; ++ks)
            bfr[j][ks] = fragld(myB, brow + j * 16 + (l & 15), ks * 64 + (l >> 4) * 16);
      }
      bh8 afr[2][2];
      #pragma unroll
      for (int i = 0; i < 2; ++i)
        #pragma unroll
        for (int ks = 0; ks < 2; ++ks)
          afr[i][ks] = fragld(myA, p * 32 + i * 16 + (l & 15), ks * 64 + (l >> 4) * 16);
      if (p == 0)      SH(0, t1, (t + 1) & 1);
      else if (p == 1) SH(1, t1, (t + 1) & 1);
      else if (p == 2) SH(2, t2, t & 1);
      else { SH(3, t2, t & 1); asm volatile("s_waitcnt vmcnt(4)" ::: "memory"); }
      __builtin_amdgcn_s_barrier();
      asm volatile("s_waitcnt lgkmcnt(0)" ::: "memory");
      __builtin_amdgcn_s_setprio(1);
      #pragma unroll
      for (int i = 0; i < 2; ++i)
        #pragma unroll
        for (int j = 0; j < 4; ++j)
          #pragma unroll
          for (int ks = 0; ks < 2; ++ks)
            acc[p * 2 + i][j] = __builtin_amdgcn_mfma_f32_16x16x32_bf16(
                afr[i][ks], bfr[j][ks], acc[p * 2 + i][j], 0, 0, 0);
      __builtin_amdgcn_s_setprio(0);
      __builtin_amdgcn_s_barrier();
    }
  }
}

// ---------------- prep kernels ----------------

static __device__ __forceinline__ float block_reduce_sum(float v, volatile float* sb, int t) {
  #pragma unroll
  for (int o = 32; o; o >>= 1) v += __shfl_xor(v, o);
  if ((t & 63) == 0) sb[t >> 6] = v;
  __syncthreads();
  float r = sb[0] + sb[1] + sb[2] + sb[3];
  __syncthreads();
  return r;
}

__global__ __launch_bounds__(256) void prep_wn(const float* __restrict__ e,
                                               unsigned short* __restrict__ wn) {
  __shared__ float sb[4];
  const int n = blockIdx.x, t = threadIdx.x;
  const float4 v = *(const float4*)(e + (size_t)n * DIM + t * 4);
  float ss = v.x * v.x + v.y * v.y + v.z * v.z + v.w * v.w;
  ss = block_reduce_sum(ss, sb, t);
  const float inv = 1.0f / fmaxf(sqrtf(ss), 1e-12f);
  u16x4 pk;
  pk[0] = f2bf(v.x * inv); pk[1] = f2bf(v.y * inv);
  pk[2] = f2bf(v.z * inv); pk[3] = f2bf(v.w * inv);
  *(u16x4*)(wn + (size_t)n * DIM + t * 4) = pk;
}

__global__ __launch_bounds__(256) void prep_xnorm(const float* __restrict__ x,
                                                  unsigned short* __restrict__ xnb) {
  __shared__ float sb[4];
  const int r = blockIdx.x, t = threadIdx.x;   // r = m*8 + b
  const float4 v = *(const float4*)(x + (size_t)r * DIM + t * 4);
  float ss = v.x * v.x + v.y * v.y + v.z * v.z + v.w * v.w;
  ss = block_reduce_sum(ss, sb, t);
  const float inv = 1.0f / fmaxf(sqrtf(ss), 1e-12f);
  const int m = r >> 3, b = r & 7;
  u16x4 pk;
  pk[0] = f2bf(v.x * inv); pk[1] = f2bf(v.y * inv);
  pk[2] = f2bf(v.z * inv); pk[3] = f2bf(v.w * inv);
  *(u16x4*)(xnb + ((size_t)b * N_TOK + m) * DIM + t * 4) = pk;
}

__global__ __launch_bounds__(256) void prep_xt(const float* __restrict__ x,
                                               unsigned short* __restrict__ XT) {
  __shared__ unsigned short tile[64][65];
  const int t = threadIdx.x;
  const int m0 = blockIdx.x * 64, d0 = blockIdx.y * 64, b = blockIdx.z;
  {
    const int ml = t >> 2, dc = (t & 3) * 16;
    const float* row = x + ((size_t)(m0 + ml) * BATCH + b) * DIM + d0 + dc;
    #pragma unroll
    for (int i = 0; i < 4; ++i) {
      float4 v = *(const float4*)(row + i * 4);
      tile[ml][dc + i * 4 + 0] = f2bf(v.x);
      tile[ml][dc + i * 4 + 1] = f2bf(v.y);
      tile[ml][dc + i * 4 + 2] = f2bf(v.z);
      tile[ml][dc + i * 4 + 3] = f2bf(v.w);
    }
  }
  __syncthreads();
  {
    const int dl = t >> 2, mc = (t & 3) * 16;
    u16x8 o0, o1;
    #pragma unroll
    for (int ii = 0; ii < 8; ++ii) {
      o0[ii] = tile[mc + ii][dl];
      o1[ii] = tile[mc + 8 + ii][dl];
    }
    unsigned short* dst = XT + ((size_t)b * DIM + d0 + dl) * (size_t)N_TOK + m0 + mc;
    *(u16x8*)dst = o0;
    *(u16x8*)(dst + 8) = o1;
  }
}

// ---------------- GEMM A (8-phase): S = wn . xn^T ; P = exp(S) ; row denominators ----------------

__global__ __launch_bounds__(512, 2) void kA8(
    const unsigned short* __restrict__ wn, const unsigned short* __restrict__ xnb,
    unsigned short* __restrict__ Pp, float* __restrict__ pden, int Mc, int c0) {
  __shared__ __align__(16) unsigned char lds[131072];
  __shared__ float pd[256][4];

  const int t = threadIdx.x, l = t & 63, w = t >> 6;
  const int wm = w >> 2, wn4 = w & 3;
  const int q0 = blockIdx.x * 256;
  const int m0l = blockIdx.y * 256;
  const int b = blockIdx.z;
  const int m0g = c0 + m0l;

  f4 acc[8][4];
  #pragma unroll
  for (int i = 0; i < 8; ++i)
    #pragma unroll
    for (int j = 0; j < 4; ++j) acc[i][j] = (f4)0.0f;

  gemm8_core(lds,
             (const unsigned char*)(wn + (size_t)q0 * DIM), (size_t)DIM * 2,
             (const unsigned char*)(xnb + ((size_t)b * N_TOK + m0g) * DIM), (size_t)DIM * 2,
             DIM / 64, w, l, acc);

  __syncthreads();

  // epilogue: P = exp(S) (scores in [-1,1]; no max needed), bf16 store + row sums
  const int lr = (l >> 4) * 4, lc = l & 15;
  float ra[8][4];
  #pragma unroll
  for (int i = 0; i < 8; ++i)
    #pragma unroll
    for (int e = 0; e < 4; ++e) ra[i][e] = 0.0f;

  #pragma unroll
  for (int mi = 0; mi < 8; ++mi) {
    #pragma unroll
    for (int nj = 0; nj < 4; ++nj) {
      const int m = m0l + wn4 * 64 + nj * 16 + lc;
      #pragma unroll
      for (int e = 0; e < 4; ++e) {
        const float p = __expf(acc[mi][nj][e]);
        ra[mi][e] += p;
        const int q = q0 + wm * 128 + mi * 16 + lr + e;
        Pp[((size_t)b * N_TOK + q) * (size_t)Mc + m] = f2bf(p);
      }
    }
  }
  #pragma unroll
  for (int mi = 0; mi < 8; ++mi)
    #pragma unroll
    for (int e = 0; e < 4; ++e) {
      float s = ra[mi][e];
      s += __shfl_xor(s, 1); s += __shfl_xor(s, 2);
      s += __shfl_xor(s, 4); s += __shfl_xor(s, 8);
      if (lc == 0) pd[wm * 128 + mi * 16 + lr + e][wn4] = s;
    }
  __syncthreads();
  if (t < 256)
    pden[((size_t)b * N_TOK + q0 + t) * 8 + (c0 >> 8) + blockIdx.y] =
        pd[t][0] + pd[t][1] + pd[t][2] + pd[t][3];
}

// ---------------- GEMM B (8-phase): O += P . V ; final applies 1/den and +x ----------------

template <int ACC, int FINAL>
__global__ __launch_bounds__(512, 2) void kB8(const unsigned short* __restrict__ Pp,
    const unsigned short* __restrict__ XT, const float* __restrict__ x,
    const float* __restrict__ pden, float* __restrict__ out, int Mc, int c0) {
  __shared__ __align__(16) unsigned char lds[131072];
  __shared__ float rden_s[256];

  const int t = threadIdx.x, l = t & 63, w = t >> 6;
  const int wm = w >> 2, wn4 = w & 3;
  const int q0 = blockIdx.x * 256;
  const int d0 = blockIdx.y * 256;
  const int b = blockIdx.z;

  f4 acc[8][4];
  #pragma unroll
  for (int i = 0; i < 8; ++i)
    #pragma unroll
    for (int j = 0; j < 4; ++j) acc[i][j] = (f4)0.0f;

  gemm8_core(lds,
             (const unsigned char*)Pp + ((size_t)b * N_TOK + q0) * (size_t)Mc * 2, (size_t)Mc * 2,
             (const unsigned char*)XT + (((size_t)b * DIM + d0) * (size_t)N_TOK + c0) * 2,
             (size_t)N_TOK * 2,
             Mc / 64, w, l, acc);

  __syncthreads();

  if (FINAL) {
    if (t < 256) {
      const float* pp = pden + ((size_t)b * N_TOK + q0 + t) * 8;
      float s = 0.0f;
      #pragma unroll
      for (int i = 0; i < 8; ++i) s += pp[i];
      rden_s[t] = 1.0f / s;
    }
    __syncthreads();
  }

  const int lr = (l >> 4) * 4, lc = l & 15;
  #pragma unroll
  for (int nj = 0; nj < 4; ++nj) {
    const int d = d0 + wn4 * 64 + nj * 16 + lc;
    #pragma unroll
    for (int mi = 0; mi < 8; ++mi)
      #pragma unroll
      for (int e = 0; e < 4; ++e) {
        const int rl = wm * 128 + mi * 16 + lr + e;
        const size_t oi = (size_t)(q0 + rl) * (BATCH * DIM) + (size_t)b * DIM + d;
        float v = acc[mi][nj][e];
        if (ACC) v += out[oi];
        if (FINAL) v = v * rden_s[rl] + x[oi];
        out[oi] = v;
      }
  }
}

// ---------------- final: out = LN(y) * gamma + beta  (y already = O/den + x) ----------------

__global__ __launch_bounds__(256) void kLN(const float* __restrict__ gamma,
    const float* __restrict__ beta, float* __restrict__ out) {
  __shared__ float sb[8];
  const int r = blockIdx.x;            // r = n*8 + b
  const int t = threadIdx.x;

  const size_t base = (size_t)r * DIM;
  const float4 y4 = *(const float4*)(out + base + t * 4);
  const float y0 = y4.x, y1 = y4.y, y2 = y4.z, y3 = y4.w;

  float s1 = y0 + y1 + y2 + y3;
  float s2 = y0 * y0 + y1 * y1 + y2 * y2 + y3 * y3;
  #pragma unroll
  for (int o = 32; o; o >>= 1) { s1 += __shfl_xor(s1, o); s2 += __shfl_xor(s2, o); }
  if ((t & 63) == 0) { sb[t >> 6] = s1; sb[4 + (t >> 6)] = s2; }
  __syncthreads();
  s1 = sb[0] + sb[1] + sb[2] + sb[3];
  s2 = sb[4] + sb[5] + sb[6] + sb[7];

  const float mean = s1 * (1.0f / DIM);
  const float var = s2 * (1.0f / DIM) - mean * mean;
  const float rstd = rsqrtf(var + 1e-5f);

  const float4 g4 = *(const float4*)(gamma + t * 4);
  const float4 b4 = *(const float4*)(beta + t * 4);
  float4 rr;
  rr.x = (y0 - mean) * rstd * g4.x + b4.x;
  rr.y = (y1 - mean) * rstd * g4.y + b4.y;
  rr.z = (y2 - mean) * rstd * g4.z + b4.z;
  rr.w = (y3 - mean) * rstd * g4.w + b4.w;
  *(float4*)(out + base + t * 4) = rr;
}

// ---------------- launch ----------------

extern "C" void kernel_launch(void* const* d_in, const int* in_sizes, int n_in,
                              void* d_out, int out_size, void* d_ws, size_t ws_size,
                              hipStream_t stream) {
  (void)in_sizes; (void)n_in; (void)out_size;
  const float* x     = (const float*)d_in[0];
  const float* embed = (const float*)d_in[1];
  const float* gamma = (const float*)d_in[2];
  const float* beta  = (const float*)d_in[3];
  float* out = (float*)d_out;

  size_t off = 0;
  char* ws = (char*)d_ws;
  auto take = [&](size_t bytes) { char* p = ws + off; off += bytes; return p; };
  unsigned short* XT  = (unsigned short*)take((size_t)BATCH * DIM * N_TOK * 2);   // 33.5 MB
  unsigned short* xnb = (unsigned short*)take((size_t)BATCH * N_TOK * DIM * 2);   // 33.5 MB
  unsigned short* wnb = (unsigned short*)take((size_t)N_TOK * DIM * 2);           //  4.2 MB
  float* pden = (float*)take((size_t)BATCH * N_TOK * 8 * 4);                      //  0.5 MB
  const size_t fixed = off;

  int Mc = 2048;
  while (Mc > 256 && fixed + (size_t)BATCH * N_TOK * Mc * 2 > ws_size) Mc >>= 1;
  unsigned short* Pp = (unsigned short*)take((size_t)BATCH * N_TOK * Mc * 2);

  prep_wn<<<N_TOK, 256, 0, stream>>>(embed, wnb);
  prep_xnorm<<<N_TOK * BATCH, 256, 0, stream>>>(x, xnb);
  prep_xt<<<dim3(N_TOK / 64, DIM / 64, BATCH), 256, 0, stream>>>(x, XT);

  const int nchunk = N_TOK / Mc;
  for (int ci = 0; ci < nchunk; ++ci) {
    const int c0 = ci * Mc;
    kA8<<<dim3(8, Mc / 256, BATCH), 512, 0, stream>>>(wnb, xnb, Pp, pden, Mc, c0);
    const bool first = (ci == 0), last = (ci == nchunk - 1);
    if (first && last)
      kB8<0, 1><<<dim3(8, 4, BATCH), 512, 0, stream>>>(Pp, XT, x, pden, out, Mc, c0);
    else if (first)
      kB8<0, 0><<<dim3(8, 4, BATCH), 512, 0, stream>>>(Pp, XT, x, pden, out, Mc, c0);
    else if (last)
      kB8<1, 1><<<dim3(8, 4, BATCH), 512, 0, stream>>>(Pp, XT, x, pden, out, Mc, c0);
    else
      kB8<1, 0><<<dim3(8, 4, BATCH), 512, 0, stream>>>(Pp, XT, x, pden, out, Mc, c0);
  }
  kLN<<<N_TOK * BATCH, 256, 0, stream>>>(gamma, beta, out);
}

// Round 4
// 262.027 us; speedup vs baseline: 1.1073x; 1.1073x over previous
//
#include <hip/hip_runtime.h>
#include <hip/hip_bf16.h>

typedef short bh8 __attribute__((ext_vector_type(8)));
typedef float f4 __attribute__((ext_vector_type(4)));
typedef unsigned short u16x8 __attribute__((ext_vector_type(8)));
typedef unsigned short u16x4 __attribute__((ext_vector_type(4)));

#define N_TOK 2048
#define BATCH 8
#define DIM   1024

// f32 -> bf16 round-to-nearest-even (finite values only)
static __device__ __forceinline__ unsigned short f2bf(float f) {
  unsigned int b = __float_as_uint(f);
  b += 0x7FFFu + ((b >> 16) & 1u);
  return (unsigned short)(b >> 16);
}

static __device__ __forceinline__ void gld16(const void* g, void* lds) {
  __builtin_amdgcn_global_load_lds(
      (const __attribute__((address_space(1))) unsigned int*)g,
      (__attribute__((address_space(3))) unsigned int*)lds, 16, 0, 0);
}

// Stage a [128 rows x 64 k] bf16 half-tile into a 16 KB LDS region with 512
// threads (2 x gld16 each).  Linear LDS dest, XOR-swizzled per-lane global
// source (G21): LDS[row*128 + (kb ^ ((row&7)<<4))] = G[row][kb].
static __device__ __forceinline__ void stage_half(const unsigned char* g, size_t ldb,
                                                  unsigned char* ldsreg, int w, int l) {
  const int rgrp = l >> 3;                       // row within 8-row granule
  const int srcb = (((l & 7) ^ rgrp) << 4);      // swizzled byte offset in row
  gld16(g + (size_t)(w * 8 + rgrp) * ldb + srcb, ldsreg + w * 1024);
  gld16(g + (size_t)((w + 8) * 8 + rgrp) * ldb + srcb, ldsreg + (w + 8) * 1024);
}

// read one 16x16x32 fragment (8 consecutive k at one row), swizzle-aware
static __device__ __forceinline__ bh8 fragld(const unsigned char* lds, int row, int kbyte) {
  return *(const bh8*)(lds + row * 128 + (kbyte ^ ((row & 7) << 4)));
}

// ---- 8-phase PAIR-scheduled 256x256 K-loop core (T2+T3+T4+T5). ----
// One iteration = 2 K-tiles: tA=2i (dbuf0), tB=2i+1 (dbuf1); 8 phases.
// dbuf layout: A0@0 A1@16K B0@32K B1@48K (each 16KB = 128 rows x 64 k).
// Reads: ph1: B(tA) all 8 frags + A(tA) quad0; ph2-4: A(tA) quads 1-3;
//        ph5: B(tB) all + A(tB) quad0;          ph6-8: A(tB) quads 1-3.
// Stages (each SH = 2 loads/thread), region free-time verified:
//   ph1: A0(tB)         [dbuf1.A last read prev ph8]
//   ph2: A1(tB), B0(tA+2) [dbuf0.B last read ph1]
//   ph3: B1(tA+2)
//   ph4: --            + s_waitcnt vmcnt(4)  (drains B(tB),A(tB); keeps B(tA+2))
//   ph5: A0(tA+2)       [dbuf0.A last read ph4]
//   ph6: A1(tA+2)
//   ph7: B0(tB+2)       [dbuf1.B last read ph5]
//   ph8: B1(tB+2)      + s_waitcnt vmcnt(4)  (drains B,A(tA+2); keeps B(tB+2))
// Outstanding-count invariant per iter: 4,6,10,12 -> 4,6,8,10,12 -> 4.
// Issue-to-wait distance: B-halves 5-6 phases, A-halves ~3 phases.
static __device__ __forceinline__ void gemm8_core(unsigned char* lds,
    const unsigned char* Ab, size_t lda, const unsigned char* Bb, size_t ldb,
    int nk, int w, int l, f4 acc[8][4]) {
  const int wm = w >> 2, wn4 = w & 3;
  auto SH = [&](int part, int tile) {
    const int src = (tile < nk) ? tile : (tile & 1);  // clamp: dummy stage into dead region
    const unsigned char* g = (part < 2 ? Ab + (size_t)(part * 128) * lda
                                       : Bb + (size_t)((part - 2) * 128) * ldb)
                             + (size_t)src * 128;
    stage_half(g, part < 2 ? lda : ldb,
               lds + (tile & 1) * 65536 + part * 16384, w, l);
  };

  // prologue: tile0 fully + tile1 B-halves in flight
  SH(0, 0); SH(1, 0); SH(2, 0); SH(3, 0); SH(2, 1); SH(3, 1);
  asm volatile("s_waitcnt vmcnt(4)" ::: "memory");   // drain tile0; keep B(1)
  __builtin_amdgcn_s_barrier();

  const int np = nk >> 1;
  for (int i = 0; i < np; ++i) {
    #pragma unroll
    for (int h = 0; h < 2; ++h) {                    // h=0: tile tA (dbuf0), h=1: tB (dbuf1)
      unsigned char* buf = lds + h * 65536;
      const unsigned char* myA = buf + wm * 16384;
      const unsigned char* myB = buf + 32768 + (wn4 >> 1) * 16384;
      const int brow = (wn4 & 1) * 64;
      bh8 bfr[4][2];
      #pragma unroll
      for (int p = 0; p < 4; ++p) {
        bh8 afr[2][2];
        #pragma unroll
        for (int i2 = 0; i2 < 2; ++i2)
          #pragma unroll
          for (int ks = 0; ks < 2; ++ks)
            afr[i2][ks] = fragld(myA, p * 32 + i2 * 16 + (l & 15), ks * 64 + (l >> 4) * 16);
        if (p == 0) {
          #pragma unroll
          for (int j = 0; j < 4; ++j)
            #pragma unroll
            for (int ks = 0; ks < 2; ++ks)
              bfr[j][ks] = fragld(myB, brow + j * 16 + (l & 15), ks * 64 + (l >> 4) * 16);
        }
        if (h == 0) {
          if (p == 0) SH(0, 2 * i + 1);
          else if (p == 1) { SH(1, 2 * i + 1); SH(2, 2 * i + 2); }
          else if (p == 2) SH(3, 2 * i + 2);
          else asm volatile("s_waitcnt vmcnt(4)" ::: "memory");
        } else {
          if (p == 0) SH(0, 2 * i + 2);
          else if (p == 1) SH(1, 2 * i + 2);
          else if (p == 2) SH(2, 2 * i + 3);
          else { SH(3, 2 * i + 3); asm volatile("s_waitcnt vmcnt(4)" ::: "memory"); }
        }
        __builtin_amdgcn_s_barrier();
        asm volatile("s_waitcnt lgkmcnt(0)" ::: "memory");
        __builtin_amdgcn_sched_barrier(0);           // rule #18: pin MFMA below the wait
        __builtin_amdgcn_s_setprio(1);
        #pragma unroll
        for (int i2 = 0; i2 < 2; ++i2)
          #pragma unroll
          for (int j = 0; j < 4; ++j)
            #pragma unroll
            for (int ks = 0; ks < 2; ++ks)
              acc[p * 2 + i2][j] = __builtin_amdgcn_mfma_f32_16x16x32_bf16(
                  afr[i2][ks], bfr[j][ks], acc[p * 2 + i2][j], 0, 0, 0);
        __builtin_amdgcn_s_setprio(0);
        __builtin_amdgcn_s_barrier();
      }
    }
  }
  asm volatile("s_waitcnt vmcnt(0)" ::: "memory");   // drain tail dummy stages
}

// ---------------- prep kernels ----------------

static __device__ __forceinline__ float block_reduce_sum(float v, volatile float* sb, int t) {
  #pragma unroll
  for (int o = 32; o; o >>= 1) v += __shfl_xor(v, o);
  if ((t & 63) == 0) sb[t >> 6] = v;
  __syncthreads();
  float r = sb[0] + sb[1] + sb[2] + sb[3];
  __syncthreads();
  return r;
}

__global__ __launch_bounds__(256) void prep_wn(const float* __restrict__ e,
                                               unsigned short* __restrict__ wn) {
  __shared__ float sb[4];
  const int n = blockIdx.x, t = threadIdx.x;
  const float4 v = *(const float4*)(e + (size_t)n * DIM + t * 4);
  float ss = v.x * v.x + v.y * v.y + v.z * v.z + v.w * v.w;
  ss = block_reduce_sum(ss, sb, t);
  const float inv = 1.0f / fmaxf(sqrtf(ss), 1e-12f);
  u16x4 pk;
  pk[0] = f2bf(v.x * inv); pk[1] = f2bf(v.y * inv);
  pk[2] = f2bf(v.z * inv); pk[3] = f2bf(v.w * inv);
  *(u16x4*)(wn + (size_t)n * DIM + t * 4) = pk;
}

__global__ __launch_bounds__(256) void prep_xnorm(const float* __restrict__ x,
                                                  unsigned short* __restrict__ xnb) {
  __shared__ float sb[4];
  const int r = blockIdx.x, t = threadIdx.x;   // r = m*8 + b
  const float4 v = *(const float4*)(x + (size_t)r * DIM + t * 4);
  float ss = v.x * v.x + v.y * v.y + v.z * v.z + v.w * v.w;
  ss = block_reduce_sum(ss, sb, t);
  const float inv = 1.0f / fmaxf(sqrtf(ss), 1e-12f);
  const int m = r >> 3, b = r & 7;
  u16x4 pk;
  pk[0] = f2bf(v.x * inv); pk[1] = f2bf(v.y * inv);
  pk[2] = f2bf(v.z * inv); pk[3] = f2bf(v.w * inv);
  *(u16x4*)(xnb + ((size_t)b * N_TOK + m) * DIM + t * 4) = pk;
}

__global__ __launch_bounds__(256) void prep_xt(const float* __restrict__ x,
                                               unsigned short* __restrict__ XT) {
  __shared__ unsigned short tile[64][65];
  const int t = threadIdx.x;
  const int m0 = blockIdx.x * 64, d0 = blockIdx.y * 64, b = blockIdx.z;
  {
    const int ml = t >> 2, dc = (t & 3) * 16;
    const float* row = x + ((size_t)(m0 + ml) * BATCH + b) * DIM + d0 + dc;
    #pragma unroll
    for (int i = 0; i < 4; ++i) {
      float4 v = *(const float4*)(row + i * 4);
      tile[ml][dc + i * 4 + 0] = f2bf(v.x);
      tile[ml][dc + i * 4 + 1] = f2bf(v.y);
      tile[ml][dc + i * 4 + 2] = f2bf(v.z);
      tile[ml][dc + i * 4 + 3] = f2bf(v.w);
    }
  }
  __syncthreads();
  {
    const int dl = t >> 2, mc = (t & 3) * 16;
    u16x8 o0, o1;
    #pragma unroll
    for (int ii = 0; ii < 8; ++ii) {
      o0[ii] = tile[mc + ii][dl];
      o1[ii] = tile[mc + 8 + ii][dl];
    }
    unsigned short* dst = XT + ((size_t)b * DIM + d0 + dl) * (size_t)N_TOK + m0 + mc;
    *(u16x8*)dst = o0;
    *(u16x8*)(dst + 8) = o1;
  }
}

// ---------------- GEMM A (8-phase): S = wn . xn^T ; P = exp(S) ; row denominators ----------------

__global__ __launch_bounds__(512, 2) void kA8(
    const unsigned short* __restrict__ wn, const unsigned short* __restrict__ xnb,
    unsigned short* __restrict__ Pp, float* __restrict__ pden, int Mc, int c0) {
  __shared__ __align__(16) unsigned char lds[131072];
  __shared__ float pd[256][4];

  const int t = threadIdx.x, l = t & 63, w = t >> 6;
  const int wm = w >> 2, wn4 = w & 3;

  // T1: XCD-aware bijective remap (grid (8, Mc/256, 8)).  Same-B-panel blocks
  // (shared (y,z)) land on one XCD via diagonal g=(y+z)&7.  Only for Mc=2048.
  int xx, yy, zz;
  if (Mc == 2048) {
    const int lin = blockIdx.x + 8 * (blockIdx.y + 8 * blockIdx.z);
    const int g = lin & 7, s = lin >> 3;
    zz = s & 7; xx = s >> 3; yy = (g - zz) & 7;
  } else {
    xx = blockIdx.x; yy = blockIdx.y; zz = blockIdx.z;
  }
  const int q0 = xx * 256;
  const int m0l = yy * 256;
  const int b = zz;
  const int m0g = c0 + m0l;

  f4 acc[8][4];
  #pragma unroll
  for (int i = 0; i < 8; ++i)
    #pragma unroll
    for (int j = 0; j < 4; ++j) acc[i][j] = (f4)0.0f;

  gemm8_core(lds,
             (const unsigned char*)(wn + (size_t)q0 * DIM), (size_t)DIM * 2,
             (const unsigned char*)(xnb + ((size_t)b * N_TOK + m0g) * DIM), (size_t)DIM * 2,
             DIM / 64, w, l, acc);

  __syncthreads();

  // epilogue: P = exp(S) (scores in [-1,1]; no max needed), bf16 store + row sums
  const int lr = (l >> 4) * 4, lc = l & 15;
  float ra[8][4];
  #pragma unroll
  for (int i = 0; i < 8; ++i)
    #pragma unroll
    for (int e = 0; e < 4; ++e) ra[i][e] = 0.0f;

  #pragma unroll
  for (int mi = 0; mi < 8; ++mi) {
    #pragma unroll
    for (int nj = 0; nj < 4; ++nj) {
      const int m = m0l + wn4 * 64 + nj * 16 + lc;
      #pragma unroll
      for (int e = 0; e < 4; ++e) {
        const float p = __expf(acc[mi][nj][e]);
        ra[mi][e] += p;
        const int q = q0 + wm * 128 + mi * 16 + lr + e;
        Pp[((size_t)b * N_TOK + q) * (size_t)Mc + m] = f2bf(p);
      }
    }
  }
  #pragma unroll
  for (int mi = 0; mi < 8; ++mi)
    #pragma unroll
    for (int e = 0; e < 4; ++e) {
      float s = ra[mi][e];
      s += __shfl_xor(s, 1); s += __shfl_xor(s, 2);
      s += __shfl_xor(s, 4); s += __shfl_xor(s, 8);
      if (lc == 0) pd[wm * 128 + mi * 16 + lr + e][wn4] = s;
    }
  __syncthreads();
  if (t < 256)
    pden[((size_t)b * N_TOK + q0 + t) * 8 + (c0 >> 8) + yy] =
        pd[t][0] + pd[t][1] + pd[t][2] + pd[t][3];
}

// ---------------- GEMM B (8-phase): O += P . V ; final applies 1/den and +x ----------------

template <int ACC, int FINAL>
__global__ __launch_bounds__(512, 2) void kB8(const unsigned short* __restrict__ Pp,
    const unsigned short* __restrict__ XT, const float* __restrict__ x,
    const float* __restrict__ pden, float* __restrict__ out, int Mc, int c0) {
  __shared__ __align__(16) unsigned char lds[131072];
  __shared__ float rden_s[256];

  const int t = threadIdx.x, l = t & 63, w = t >> 6;
  const int wm = w >> 2, wn4 = w & 3;

  // T1: XCD remap (grid (8,4,8), 256 blocks).  Each XCD owns one (d0, b&1)
  // combo: its 4 B-panels (1MB each) = 4MB = exactly one XCD L2.
  const int lin = blockIdx.x + 8 * (blockIdx.y + 4 * blockIdx.z);
  const int g = lin & 7, s = lin >> 3;
  const int q0 = (s & 7) * 256;
  const int d0 = (g & 3) * 256;
  const int b = (s >> 3) * 2 + (g >> 2);

  f4 acc[8][4];
  #pragma unroll
  for (int i = 0; i < 8; ++i)
    #pragma unroll
    for (int j = 0; j < 4; ++j) acc[i][j] = (f4)0.0f;

  gemm8_core(lds,
             (const unsigned char*)Pp + ((size_t)b * N_TOK + q0) * (size_t)Mc * 2, (size_t)Mc * 2,
             (const unsigned char*)XT + (((size_t)b * DIM + d0) * (size_t)N_TOK + c0) * 2,
             (size_t)N_TOK * 2,
             Mc / 64, w, l, acc);

  __syncthreads();

  if (FINAL) {
    if (t < 256) {
      const float* pp = pden + ((size_t)b * N_TOK + q0 + t) * 8;
      float ssum = 0.0f;
      #pragma unroll
      for (int i = 0; i < 8; ++i) ssum += pp[i];
      rden_s[t] = 1.0f / ssum;
    }
    __syncthreads();
  }

  const int lr = (l >> 4) * 4, lc = l & 15;
  #pragma unroll
  for (int nj = 0; nj < 4; ++nj) {
    const int d = d0 + wn4 * 64 + nj * 16 + lc;
    #pragma unroll
    for (int mi = 0; mi < 8; ++mi)
      #pragma unroll
      for (int e = 0; e < 4; ++e) {
        const int rl = wm * 128 + mi * 16 + lr + e;
        const size_t oi = (size_t)(q0 + rl) * (BATCH * DIM) + (size_t)b * DIM + d;
        float v = acc[mi][nj][e];
        if (ACC) v += out[oi];
        if (FINAL) v = v * rden_s[rl] + x[oi];
        out[oi] = v;
      }
  }
}

// ---------------- final: out = LN(y) * gamma + beta  (y already = O/den + x) ----------------

__global__ __launch_bounds__(256) void kLN(const float* __restrict__ gamma,
    const float* __restrict__ beta, float* __restrict__ out) {
  __shared__ float sb[8];
  const int r = blockIdx.x;            // r = n*8 + b
  const int t = threadIdx.x;

  const size_t base = (size_t)r * DIM;
  const float4 y4 = *(const float4*)(out + base + t * 4);
  const float y0 = y4.x, y1 = y4.y, y2 = y4.z, y3 = y4.w;

  float s1 = y0 + y1 + y2 + y3;
  float s2 = y0 * y0 + y1 * y1 + y2 * y2 + y3 * y3;
  #pragma unroll
  for (int o = 32; o; o >>= 1) { s1 += __shfl_xor(s1, o); s2 += __shfl_xor(s2, o); }
  if ((t & 63) == 0) { sb[t >> 6] = s1; sb[4 + (t >> 6)] = s2; }
  __syncthreads();
  s1 = sb[0] + sb[1] + sb[2] + sb[3];
  s2 = sb[4] + sb[5] + sb[6] + sb[7];

  const float mean = s1 * (1.0f / DIM);
  const float var = s2 * (1.0f / DIM) - mean * mean;
  const float rstd = rsqrtf(var + 1e-5f);

  const float4 g4 = *(const float4*)(gamma + t * 4);
  const float4 b4 = *(const float4*)(beta + t * 4);
  float4 rr;
  rr.x = (y0 - mean) * rstd * g4.x + b4.x;
  rr.y = (y1 - mean) * rstd * g4.y + b4.y;
  rr.z = (y2 - mean) * rstd * g4.z + b4.z;
  rr.w = (y3 - mean) * rstd * g4.w + b4.w;
  *(float4*)(out + base + t * 4) = rr;
}

// ---------------- launch ----------------

extern "C" void kernel_launch(void* const* d_in, const int* in_sizes, int n_in,
                              void* d_out, int out_size, void* d_ws, size_t ws_size,
                              hipStream_t stream) {
  (void)in_sizes; (void)n_in; (void)out_size;
  const float* x     = (const float*)d_in[0];
  const float* embed = (const float*)d_in[1];
  const float* gamma = (const float*)d_in[2];
  const float* beta  = (const float*)d_in[3];
  float* out = (float*)d_out;

  size_t off = 0;
  char* ws = (char*)d_ws;
  auto take = [&](size_t bytes) { char* p = ws + off; off += bytes; return p; };
  unsigned short* XT  = (unsigned short*)take((size_t)BATCH * DIM * N_TOK * 2);   // 33.5 MB
  unsigned short* xnb = (unsigned short*)take((size_t)BATCH * N_TOK * DIM * 2);   // 33.5 MB
  unsigned short* wnb = (unsigned short*)take((size_t)N_TOK * DIM * 2);           //  4.2 MB
  float* pden = (float*)take((size_t)BATCH * N_TOK * 8 * 4);                      //  0.5 MB
  const size_t fixed = off;

  int Mc = 2048;
  while (Mc > 256 && fixed + (size_t)BATCH * N_TOK * Mc * 2 > ws_size) Mc >>= 1;
  unsigned short* Pp = (unsigned short*)take((size_t)BATCH * N_TOK * Mc * 2);

  prep_wn<<<N_TOK, 256, 0, stream>>>(embed, wnb);
  prep_xnorm<<<N_TOK * BATCH, 256, 0, stream>>>(x, xnb);
  prep_xt<<<dim3(N_TOK / 64, DIM / 64, BATCH), 256, 0, stream>>>(x, XT);

  const int nchunk = N_TOK / Mc;
  for (int ci = 0; ci < nchunk; ++ci) {
    const int c0 = ci * Mc;
    kA8<<<dim3(8, Mc / 256, BATCH), 512, 0, stream>>>(wnb, xnb, Pp, pden, Mc, c0);
    const bool first = (ci == 0), last = (ci == nchunk - 1);
    if (first && last)
      kB8<0, 1><<<dim3(8, 4, BATCH), 512, 0, stream>>>(Pp, XT, x, pden, out, Mc, c0);
    else if (first)
      kB8<0, 0><<<dim3(8, 4, BATCH), 512, 0, stream>>>(Pp, XT, x, pden, out, Mc, c0);
    else if (last)
      kB8<1, 1><<<dim3(8, 4, BATCH), 512, 0, stream>>>(Pp, XT, x, pden, out, Mc, c0);
    else
      kB8<1, 0><<<dim3(8, 4, BATCH), 512, 0, stream>>>(Pp, XT, x, pden, out, Mc, c0);
  }
  kLN<<<N_TOK * BATCH, 256, 0, stream>>>(gamma, beta, out);
}

// Round 5
// 181.012 us; speedup vs baseline: 1.6029x; 1.4476x over previous
//
#include <hip/hip_runtime.h>
#include <hip/hip_bf16.h>

typedef float f4 __attribute__((ext_vector_type(4)));
typedef unsigned char u8x16 __attribute__((ext_vector_type(16)));

#define N_TOK 2048
#define BATCH 8
#define DIM   1024

// ---- fp8 e4m3 (OCP on gfx950) pack helpers ----
static __device__ __forceinline__ unsigned int pk4_fp8(float a, float b, float c, float d) {
  unsigned int v = 0;
  v = __builtin_amdgcn_cvt_pk_fp8_f32(a, b, v, false);
  v = __builtin_amdgcn_cvt_pk_fp8_f32(c, d, v, true);
  return v;
}
static __device__ __forceinline__ unsigned char fp8_1(float a) {
  return (unsigned char)(__builtin_amdgcn_cvt_pk_fp8_f32(a, a, 0, false) & 0xFF);
}

static __device__ __forceinline__ void gld16(const void* g, void* lds) {
  __builtin_amdgcn_global_load_lds(
      (const __attribute__((address_space(1))) unsigned int*)g,
      (__attribute__((address_space(3))) unsigned int*)lds, 16, 0, 0);
}

// Stage a [128 rows x 128 byte] fp8 tile into 16 KB LDS with 256 threads
// (4 x gld16 each).  Linear LDS dest, XOR-swizzled per-lane global source
// (G21): LDS[row*128 + (g16 ^ ((row&7)<<4))] = G[row][g16] per 16B granule.
static __device__ __forceinline__ void stage_tile(const unsigned char* g, size_t ldb,
                                                  unsigned char* lds, int w, int l) {
  const int rgrp = l >> 3;                       // row within 8-row granule
  const int srcb = (((l & 7) ^ rgrp) << 4);      // swizzled byte offset in row
  #pragma unroll
  for (int gi = 0; gi < 4; ++gi) {
    int rb = (gi * 4 + w) * 8;                   // wave-granule base row
    gld16(g + (size_t)(rb + rgrp) * ldb + srcb, lds + (gi * 4 + w) * 1024);
  }
}

// read one 16x16x32 fp8 fragment (8 consecutive k at one row), swizzle-aware.
// kbyte is 8B-aligned; XOR touches bits 4-6 only, so the 8B stays contiguous.
static __device__ __forceinline__ long fragld8(const unsigned char* lds, int row, int kbyte) {
  return *(const long*)(lds + row * 128 + (kbyte ^ ((row & 7) << 4)));
}

// shared fp8 K-loop (m97 structure: 2-barrier, BK=128, acc 4x4 per wave)
static __device__ __forceinline__ void gemm_fp8(unsigned char* sA, unsigned char* sB,
    const unsigned char* Ab, size_t lda, const unsigned char* Bb, size_t ldb,
    int nk, int w, int l, int wr, int wc, f4 acc[4][4]) {
  for (int kk = 0; kk < nk; ++kk) {
    stage_tile(Ab + (size_t)kk * 128, lda, sA, w, l);
    stage_tile(Bb + (size_t)kk * 128, ldb, sB, w, l);
    __syncthreads();
    #pragma unroll
    for (int ks = 0; ks < 4; ++ks) {
      const int kb = ks * 32 + (l >> 4) * 8;
      long af[4], bf[4];
      #pragma unroll
      for (int i = 0; i < 4; ++i)
        af[i] = fragld8(sA, wr * 64 + i * 16 + (l & 15), kb);
      #pragma unroll
      for (int j = 0; j < 4; ++j)
        bf[j] = fragld8(sB, wc * 64 + j * 16 + (l & 15), kb);
      #pragma unroll
      for (int i = 0; i < 4; ++i)
        #pragma unroll
        for (int j = 0; j < 4; ++j)
          acc[i][j] = __builtin_amdgcn_mfma_f32_16x16x32_fp8_fp8(af[i], bf[j], acc[i][j], 0, 0, 0);
    }
    __syncthreads();
  }
}

// ---------------- prep kernels ----------------

static __device__ __forceinline__ float block_reduce_sum(float v, volatile float* sb, int t) {
  #pragma unroll
  for (int o = 32; o; o >>= 1) v += __shfl_xor(v, o);
  if ((t & 63) == 0) sb[t >> 6] = v;
  __syncthreads();
  float r = sb[0] + sb[1] + sb[2] + sb[3];
  __syncthreads();
  return r;
}

// embed -> normalized fp8 wn  (one block per row)
__global__ __launch_bounds__(256) void prep_wn(const float* __restrict__ e,
                                               unsigned char* __restrict__ wn) {
  __shared__ float sb[4];
  const int n = blockIdx.x, t = threadIdx.x;
  const float4 v = *(const float4*)(e + (size_t)n * DIM + t * 4);
  float ss = v.x * v.x + v.y * v.y + v.z * v.z + v.w * v.w;
  ss = block_reduce_sum(ss, sb, t);
  const float inv = 1.0f / fmaxf(sqrtf(ss), 1e-12f);
  *(unsigned int*)(wn + (size_t)n * DIM + t * 4) =
      pk4_fp8(v.x * inv, v.y * inv, v.z * inv, v.w * inv);
}

// x row (m,b) -> normalized fp8 xn[b][m][d]  (one block per row)
__global__ __launch_bounds__(256) void prep_xnorm(const float* __restrict__ x,
                                                  unsigned char* __restrict__ xnb) {
  __shared__ float sb[4];
  const int r = blockIdx.x, t = threadIdx.x;   // r = m*8 + b
  const float4 v = *(const float4*)(x + (size_t)r * DIM + t * 4);
  float ss = v.x * v.x + v.y * v.y + v.z * v.z + v.w * v.w;
  ss = block_reduce_sum(ss, sb, t);
  const float inv = 1.0f / fmaxf(sqrtf(ss), 1e-12f);
  const int m = r >> 3, b = r & 7;
  *(unsigned int*)(xnb + ((size_t)b * N_TOK + m) * DIM + t * 4) =
      pk4_fp8(v.x * inv, v.y * inv, v.z * inv, v.w * inv);
}

// x[m][b][d] -> XT[b][d][m] fp8 (raw, un-normalized: this is V)
__global__ __launch_bounds__(256) void prep_xt(const float* __restrict__ x,
                                               unsigned char* __restrict__ XT) {
  __shared__ unsigned char tile[64][72];
  const int t = threadIdx.x;
  const int m0 = blockIdx.x * 64, d0 = blockIdx.y * 64, b = blockIdx.z;
  {
    const int ml = t >> 2, dc = (t & 3) * 16;
    const float* row = x + ((size_t)(m0 + ml) * BATCH + b) * DIM + d0 + dc;
    #pragma unroll
    for (int i = 0; i < 4; ++i) {
      float4 v = *(const float4*)(row + i * 4);
      *(unsigned int*)&tile[ml][dc + i * 4] = pk4_fp8(v.x, v.y, v.z, v.w);
    }
  }
  __syncthreads();
  {
    const int dl = t >> 2, mc = (t & 3) * 16;
    u8x16 o;
    #pragma unroll
    for (int ii = 0; ii < 16; ++ii) o[ii] = tile[mc + ii][dl];
    *(u8x16*)(XT + ((size_t)b * DIM + d0 + dl) * (size_t)N_TOK + m0 + mc) = o;
  }
}

// ---------------- GEMM A: S = wn . xn^T ; P = exp(S) fp8 ; row denominators ----------------

__global__ __launch_bounds__(256, 3) void kA(
    const unsigned char* __restrict__ wn, const unsigned char* __restrict__ xnb,
    unsigned char* __restrict__ Pp, float* __restrict__ pden, int Mc, int c0) {
  __shared__ __align__(16) unsigned char sA[16384];
  __shared__ __align__(16) unsigned char sB[16384];
  __shared__ float pd[128][2];

  const int t = threadIdx.x, l = t & 63, w = t >> 6;
  const int wr = w >> 1, wc = w & 1;

  // T1: chunked XCD swizzle (grid (16, Mc/128, 8); nwg % 8 == 0 -> bijective).
  // Each XCD owns one batch b; x fastest within -> B-panel reuse in its L2.
  const int gy = Mc >> 7;
  const int nwg = 16 * gy * 8;
  const int lin = blockIdx.x + 16 * (blockIdx.y + gy * blockIdx.z);
  const int wg = (lin & 7) * (nwg >> 3) + (lin >> 3);
  const int xx = wg & 15, yy = (wg >> 4) % gy, zz = (wg >> 4) / gy;

  const int q0 = xx * 128;
  const int m0l = yy * 128;
  const int b = zz;
  const int m0g = c0 + m0l;

  f4 acc[4][4];
  #pragma unroll
  for (int i = 0; i < 4; ++i)
    #pragma unroll
    for (int j = 0; j < 4; ++j) acc[i][j] = (f4)0.0f;

  gemm_fp8(sA, sB,
           wn + (size_t)q0 * DIM, DIM,
           xnb + ((size_t)b * N_TOK + m0g) * DIM, DIM,
           DIM / 128, w, l, wr, wc, acc);

  // epilogue: P = exp(S) (scores in [-1,1]; no max needed), fp8 store + row sums
  float ra[4][4];
  #pragma unroll
  for (int i = 0; i < 4; ++i)
    #pragma unroll
    for (int e = 0; e < 4; ++e) ra[i][e] = 0.0f;

  #pragma unroll
  for (int j = 0; j < 4; ++j) {
    const int cl = wc * 64 + j * 16 + (l & 15);  // local m col
    #pragma unroll
    for (int i = 0; i < 4; ++i)
      #pragma unroll
      for (int e = 0; e < 4; ++e) {
        const float p = __expf(acc[i][j][e]);
        ra[i][e] += p;
        const int row = wr * 64 + i * 16 + (l >> 4) * 4 + e;  // local q
        Pp[((size_t)b * N_TOK + q0 + row) * (size_t)Mc + m0l + cl] = fp8_1(p);
      }
  }
  #pragma unroll
  for (int i = 0; i < 4; ++i)
    #pragma unroll
    for (int e = 0; e < 4; ++e) {
      float s = ra[i][e];
      s += __shfl_xor(s, 1); s += __shfl_xor(s, 2);
      s += __shfl_xor(s, 4); s += __shfl_xor(s, 8);
      if ((l & 15) == 0) pd[wr * 64 + i * 16 + (l >> 4) * 4 + e][wc] = s;
    }
  __syncthreads();
  if (t < 128)
    pden[((size_t)b * N_TOK + q0 + t) * 16 + (c0 >> 7) + yy] = pd[t][0] + pd[t][1];
}

// ---------------- GEMM B: O += P . V  (V = XT^T); final applies 1/den and +x ----------------

template <int ACC, int FINAL>
__global__ __launch_bounds__(256, 3) void kB(const unsigned char* __restrict__ Pp,
    const unsigned char* __restrict__ XT, const float* __restrict__ x,
    const float* __restrict__ pden, float* __restrict__ out, int Mc, int c0) {
  __shared__ __align__(16) unsigned char sA[16384];
  __shared__ __align__(16) unsigned char sB[16384];
  __shared__ float rden_s[128];

  const int t = threadIdx.x, l = t & 63, w = t >> 6;
  const int wr = w >> 1, wc = w & 1;

  // T1: chunked XCD swizzle (grid (16,8,8), 1024 blocks): XCD c owns b=c;
  // 16 consecutive blocks share one 256 KB XT d-panel.
  const int lin = blockIdx.x + 16 * (blockIdx.y + 8 * blockIdx.z);
  const int wg = (lin & 7) * 128 + (lin >> 3);
  const int q0 = (wg & 15) * 128;
  const int d0 = ((wg >> 4) & 7) * 128;
  const int b = wg >> 7;

  f4 acc[4][4];
  #pragma unroll
  for (int i = 0; i < 4; ++i)
    #pragma unroll
    for (int j = 0; j < 4; ++j) acc[i][j] = (f4)0.0f;

  gemm_fp8(sA, sB,
           Pp + ((size_t)b * N_TOK + q0) * (size_t)Mc, (size_t)Mc,
           XT + (((size_t)b * DIM + d0) * (size_t)N_TOK + c0), (size_t)N_TOK,
           Mc / 128, w, l, wr, wc, acc);

  if (FINAL) {
    if (t < 128) {
      const float* pp = pden + ((size_t)b * N_TOK + q0 + t) * 16;
      float s = 0.0f;
      #pragma unroll
      for (int i = 0; i < 16; ++i) s += pp[i];
      rden_s[t] = 1.0f / s;
    }
    __syncthreads();
  }

  #pragma unroll
  for (int j = 0; j < 4; ++j) {
    const int cc = d0 + wc * 64 + j * 16 + (l & 15);
    #pragma unroll
    for (int i = 0; i < 4; ++i)
      #pragma unroll
      for (int e = 0; e < 4; ++e) {
        const int rl = wr * 64 + i * 16 + (l >> 4) * 4 + e;
        const size_t oi = (size_t)(q0 + rl) * (BATCH * DIM) + (size_t)b * DIM + cc;
        float v = acc[i][j][e];
        if (ACC) v += out[oi];
        if (FINAL) v = v * rden_s[rl] + x[oi];
        out[oi] = v;
      }
  }
}

// ---------------- final: out = LN(y) * gamma + beta  (y already = O/den + x) ----------------

__global__ __launch_bounds__(256) void kLN(const float* __restrict__ gamma,
    const float* __restrict__ beta, float* __restrict__ out) {
  __shared__ float sb[8];
  const int r = blockIdx.x;            // r = n*8 + b
  const int t = threadIdx.x;

  const size_t base = (size_t)r * DIM;
  const float4 y4 = *(const float4*)(out + base + t * 4);
  const float y0 = y4.x, y1 = y4.y, y2 = y4.z, y3 = y4.w;

  float s1 = y0 + y1 + y2 + y3;
  float s2 = y0 * y0 + y1 * y1 + y2 * y2 + y3 * y3;
  #pragma unroll
  for (int o = 32; o; o >>= 1) { s1 += __shfl_xor(s1, o); s2 += __shfl_xor(s2, o); }
  if ((t & 63) == 0) { sb[t >> 6] = s1; sb[4 + (t >> 6)] = s2; }
  __syncthreads();
  s1 = sb[0] + sb[1] + sb[2] + sb[3];
  s2 = sb[4] + sb[5] + sb[6] + sb[7];

  const float mean = s1 * (1.0f / DIM);
  const float var = s2 * (1.0f / DIM) - mean * mean;
  const float rstd = rsqrtf(var + 1e-5f);

  const float4 g4 = *(const float4*)(gamma + t * 4);
  const float4 b4 = *(const float4*)(beta + t * 4);
  float4 rr;
  rr.x = (y0 - mean) * rstd * g4.x + b4.x;
  rr.y = (y1 - mean) * rstd * g4.y + b4.y;
  rr.z = (y2 - mean) * rstd * g4.z + b4.z;
  rr.w = (y3 - mean) * rstd * g4.w + b4.w;
  *(float4*)(out + base + t * 4) = rr;
}

// ---------------- launch ----------------

extern "C" void kernel_launch(void* const* d_in, const int* in_sizes, int n_in,
                              void* d_out, int out_size, void* d_ws, size_t ws_size,
                              hipStream_t stream) {
  (void)in_sizes; (void)n_in; (void)out_size;
  const float* x     = (const float*)d_in[0];
  const float* embed = (const float*)d_in[1];
  const float* gamma = (const float*)d_in[2];
  const float* beta  = (const float*)d_in[3];
  float* out = (float*)d_out;

  size_t off = 0;
  char* ws = (char*)d_ws;
  auto take = [&](size_t bytes) { char* p = ws + off; off += bytes; return p; };
  unsigned char* XT  = (unsigned char*)take((size_t)BATCH * DIM * N_TOK);   // 16.8 MB
  unsigned char* xnb = (unsigned char*)take((size_t)BATCH * N_TOK * DIM);   // 16.8 MB
  unsigned char* wnb = (unsigned char*)take((size_t)N_TOK * DIM);           //  2.1 MB
  float* pden = (float*)take((size_t)BATCH * N_TOK * 16 * 4);               //  2.1 MB
  const size_t fixed = off;

  int Mc = 2048;
  while (Mc > 128 && fixed + (size_t)BATCH * N_TOK * Mc > ws_size) Mc >>= 1;
  unsigned char* Pp = (unsigned char*)take((size_t)BATCH * N_TOK * Mc);     // 33.6 MB full

  prep_wn<<<N_TOK, 256, 0, stream>>>(embed, wnb);
  prep_xnorm<<<N_TOK * BATCH, 256, 0, stream>>>(x, xnb);
  prep_xt<<<dim3(N_TOK / 64, DIM / 64, BATCH), 256, 0, stream>>>(x, XT);

  const int nchunk = N_TOK / Mc;
  for (int ci = 0; ci < nchunk; ++ci) {
    const int c0 = ci * Mc;
    kA<<<dim3(16, Mc / 128, BATCH), 256, 0, stream>>>(wnb, xnb, Pp, pden, Mc, c0);
    const bool first = (ci == 0), last = (ci == nchunk - 1);
    if (first && last)
      kB<0, 1><<<dim3(16, 8, BATCH), 256, 0, stream>>>(Pp, XT, x, pden, out, Mc, c0);
    else if (first)
      kB<0, 0><<<dim3(16, 8, BATCH), 256, 0, stream>>>(Pp, XT, x, pden, out, Mc, c0);
    else if (last)
      kB<1, 1><<<dim3(16, 8, BATCH), 256, 0, stream>>>(Pp, XT, x, pden, out, Mc, c0);
    else
      kB<1, 0><<<dim3(16, 8, BATCH), 256, 0, stream>>>(Pp, XT, x, pden, out, Mc, c0);
  }
  kLN<<<N_TOK * BATCH, 256, 0, stream>>>(gamma, beta, out);
}

// Round 6
// 161.632 us; speedup vs baseline: 1.7951x; 1.1199x over previous
//
#include <hip/hip_runtime.h>
#include <hip/hip_bf16.h>

typedef float f4 __attribute__((ext_vector_type(4)));
typedef int i32x4 __attribute__((ext_vector_type(4)));
typedef int i32x8 __attribute__((ext_vector_type(8)));
typedef unsigned char u8x16 __attribute__((ext_vector_type(16)));

#define N_TOK 2048
#define BATCH 8
#define DIM   1024

// ---- fp8 e4m3 (OCP on gfx950) pack helpers ----
static __device__ __forceinline__ unsigned int pk4_fp8(float a, float b, float c, float d) {
  unsigned int v = 0;
  v = __builtin_amdgcn_cvt_pk_fp8_f32(a, b, v, false);
  v = __builtin_amdgcn_cvt_pk_fp8_f32(c, d, v, true);
  return v;
}
static __device__ __forceinline__ unsigned char fp8_1(float a) {
  return (unsigned char)(__builtin_amdgcn_cvt_pk_fp8_f32(a, a, 0, false) & 0xFF);
}

static __device__ __forceinline__ void gld16(const void* g, void* lds) {
  __builtin_amdgcn_global_load_lds(
      (const __attribute__((address_space(1))) unsigned int*)g,
      (__attribute__((address_space(3))) unsigned int*)lds, 16, 0, 0);
}

// Stage a [128 rows x 128 byte] fp8 tile into 16 KB LDS with 256 threads
// (4 x gld16 each).  Linear LDS dest, XOR-swizzled per-lane global source
// (G21): LDS[row*128 + (g16 ^ ((row&7)<<4))] = G[row][g16] per 16B granule.
static __device__ __forceinline__ void stage_tile(const unsigned char* g, size_t ldb,
                                                  unsigned char* lds, int w, int l) {
  const int rgrp = l >> 3;                       // row within 8-row granule
  const int srcb = (((l & 7) ^ rgrp) << 4);      // swizzled byte offset in row
  #pragma unroll
  for (int gi = 0; gi < 4; ++gi) {
    int rb = (gi * 4 + w) * 8;                   // wave-granule base row
    gld16(g + (size_t)(rb + rgrp) * ldb + srcb, lds + (gi * 4 + w) * 1024);
  }
}

// read one 16x16x128 f8f6f4 fragment: 32 consecutive k-bytes at one row,
// swizzle-aware (two independent 16B granules).  kb is 32B-aligned.
static __device__ __forceinline__ i32x8 fragld32(const unsigned char* lds, int row, int kb) {
  const unsigned char* base = lds + row * 128;
  const int swz = (row & 7) << 4;
  const i32x4 lo = *(const i32x4*)(base + (kb ^ swz));
  const i32x4 hi = *(const i32x4*)(base + ((kb + 16) ^ swz));
  i32x8 r;
  r[0] = lo[0]; r[1] = lo[1]; r[2] = lo[2]; r[3] = lo[3];
  r[4] = hi[0]; r[5] = hi[1]; r[6] = hi[2]; r[7] = hi[3];
  return r;
}

// shared MX-fp8 K-loop (m97/m148 structure: 2-barrier, BK=128, one
// mfma_scale K=128 per (i,j); E8M0 scale 0x7F == 1.0 -> numerics == plain fp8)
static __device__ __forceinline__ void gemm_mx(unsigned char* sA, unsigned char* sB,
    const unsigned char* Ab, size_t lda, const unsigned char* Bb, size_t ldb,
    int nk, int w, int l, int wr, int wc, f4 acc[4][4]) {
  for (int kk = 0; kk < nk; ++kk) {
    stage_tile(Ab + (size_t)kk * 128, lda, sA, w, l);
    stage_tile(Bb + (size_t)kk * 128, ldb, sB, w, l);
    __syncthreads();
    const int kb = (l >> 4) * 32;
    i32x8 af[4], bf[4];
    #pragma unroll
    for (int i = 0; i < 4; ++i)
      af[i] = fragld32(sA, wr * 64 + i * 16 + (l & 15), kb);
    #pragma unroll
    for (int j = 0; j < 4; ++j)
      bf[j] = fragld32(sB, wc * 64 + j * 16 + (l & 15), kb);
    #pragma unroll
    for (int i = 0; i < 4; ++i)
      #pragma unroll
      for (int j = 0; j < 4; ++j)
        acc[i][j] = __builtin_amdgcn_mfma_scale_f32_16x16x128_f8f6f4(
            af[i], bf[j], acc[i][j], 0, 0, 0, 0x7F7F7F7F, 0, 0x7F7F7F7F);
    __syncthreads();
  }
}

// ---------------- prep kernels ----------------

static __device__ __forceinline__ float block_reduce_sum(float v, volatile float* sb, int t) {
  #pragma unroll
  for (int o = 32; o; o >>= 1) v += __shfl_xor(v, o);
  if ((t & 63) == 0) sb[t >> 6] = v;
  __syncthreads();
  float r = sb[0] + sb[1] + sb[2] + sb[3];
  __syncthreads();
  return r;
}

// embed -> normalized fp8 wn  (one block per row)
__global__ __launch_bounds__(256) void prep_wn(const float* __restrict__ e,
                                               unsigned char* __restrict__ wn) {
  __shared__ float sb[4];
  const int n = blockIdx.x, t = threadIdx.x;
  const float4 v = *(const float4*)(e + (size_t)n * DIM + t * 4);
  float ss = v.x * v.x + v.y * v.y + v.z * v.z + v.w * v.w;
  ss = block_reduce_sum(ss, sb, t);
  const float inv = 1.0f / fmaxf(sqrtf(ss), 1e-12f);
  *(unsigned int*)(wn + (size_t)n * DIM + t * 4) =
      pk4_fp8(v.x * inv, v.y * inv, v.z * inv, v.w * inv);
}

// x row (m,b) -> normalized fp8 xn[b][m][d]  (one block per row)
__global__ __launch_bounds__(256) void prep_xnorm(const float* __restrict__ x,
                                                  unsigned char* __restrict__ xnb) {
  __shared__ float sb[4];
  const int r = blockIdx.x, t = threadIdx.x;   // r = m*8 + b
  const float4 v = *(const float4*)(x + (size_t)r * DIM + t * 4);
  float ss = v.x * v.x + v.y * v.y + v.z * v.z + v.w * v.w;
  ss = block_reduce_sum(ss, sb, t);
  const float inv = 1.0f / fmaxf(sqrtf(ss), 1e-12f);
  const int m = r >> 3, b = r & 7;
  *(unsigned int*)(xnb + ((size_t)b * N_TOK + m) * DIM + t * 4) =
      pk4_fp8(v.x * inv, v.y * inv, v.z * inv, v.w * inv);
}

// x[m][b][d] -> XT[b][d][m] fp8 (raw, un-normalized: this is V)
__global__ __launch_bounds__(256) void prep_xt(const float* __restrict__ x,
                                               unsigned char* __restrict__ XT) {
  __shared__ unsigned char tile[64][72];
  const int t = threadIdx.x;
  const int m0 = blockIdx.x * 64, d0 = blockIdx.y * 64, b = blockIdx.z;
  {
    const int ml = t >> 2, dc = (t & 3) * 16;
    const float* row = x + ((size_t)(m0 + ml) * BATCH + b) * DIM + d0 + dc;
    #pragma unroll
    for (int i = 0; i < 4; ++i) {
      float4 v = *(const float4*)(row + i * 4);
      *(unsigned int*)&tile[ml][dc + i * 4] = pk4_fp8(v.x, v.y, v.z, v.w);
    }
  }
  __syncthreads();
  {
    const int dl = t >> 2, mc = (t & 3) * 16;
    u8x16 o;
    #pragma unroll
    for (int ii = 0; ii < 16; ++ii) o[ii] = tile[mc + ii][dl];
    *(u8x16*)(XT + ((size_t)b * DIM + d0 + dl) * (size_t)N_TOK + m0 + mc) = o;
  }
}

// ---------------- GEMM A: S = wn . xn^T ; P = exp(S) fp8 ; row denominators ----------------

__global__ __launch_bounds__(256, 3) void kA(
    const unsigned char* __restrict__ wn, const unsigned char* __restrict__ xnb,
    unsigned char* __restrict__ Pp, float* __restrict__ pden, int Mc, int c0) {
  __shared__ __align__(16) unsigned char sA[16384];
  __shared__ __align__(16) unsigned char sB[16384];
  __shared__ float pd[128][2];

  const int t = threadIdx.x, l = t & 63, w = t >> 6;
  const int wr = w >> 1, wc = w & 1;

  // T1: chunked XCD swizzle (grid (16, Mc/128, 8); nwg % 8 == 0 -> bijective).
  // Each XCD owns one batch b; x fastest within -> B-panel reuse in its L2.
  const int gy = Mc >> 7;
  const int nwg = 16 * gy * 8;
  const int lin = blockIdx.x + 16 * (blockIdx.y + gy * blockIdx.z);
  const int wg = (lin & 7) * (nwg >> 3) + (lin >> 3);
  const int xx = wg & 15, yy = (wg >> 4) % gy, zz = (wg >> 4) / gy;

  const int q0 = xx * 128;
  const int m0l = yy * 128;
  const int b = zz;
  const int m0g = c0 + m0l;

  f4 acc[4][4];
  #pragma unroll
  for (int i = 0; i < 4; ++i)
    #pragma unroll
    for (int j = 0; j < 4; ++j) acc[i][j] = (f4)0.0f;

  gemm_mx(sA, sB,
          wn + (size_t)q0 * DIM, DIM,
          xnb + ((size_t)b * N_TOK + m0g) * DIM, DIM,
          DIM / 128, w, l, wr, wc, acc);

  // epilogue: P = exp(S) (scores in [-1,1]; no max needed), fp8 store + row sums
  float ra[4][4];
  #pragma unroll
  for (int i = 0; i < 4; ++i)
    #pragma unroll
    for (int e = 0; e < 4; ++e) ra[i][e] = 0.0f;

  #pragma unroll
  for (int j = 0; j < 4; ++j) {
    const int cl = wc * 64 + j * 16 + (l & 15);  // local m col
    #pragma unroll
    for (int i = 0; i < 4; ++i)
      #pragma unroll
      for (int e = 0; e < 4; ++e) {
        const float p = __expf(acc[i][j][e]);
        ra[i][e] += p;
        const int row = wr * 64 + i * 16 + (l >> 4) * 4 + e;  // local q
        Pp[((size_t)b * N_TOK + q0 + row) * (size_t)Mc + m0l + cl] = fp8_1(p);
      }
  }
  #pragma unroll
  for (int i = 0; i < 4; ++i)
    #pragma unroll
    for (int e = 0; e < 4; ++e) {
      float s = ra[i][e];
      s += __shfl_xor(s, 1); s += __shfl_xor(s, 2);
      s += __shfl_xor(s, 4); s += __shfl_xor(s, 8);
      if ((l & 15) == 0) pd[wr * 64 + i * 16 + (l >> 4) * 4 + e][wc] = s;
    }
  __syncthreads();
  if (t < 128)
    pden[((size_t)b * N_TOK + q0 + t) * 16 + (c0 >> 7) + yy] = pd[t][0] + pd[t][1];
}

// ---------------- GEMM B: O += P . V  (V = XT^T); final applies 1/den and +x ----------------

template <int ACC, int FINAL>
__global__ __launch_bounds__(256, 3) void kB(const unsigned char* __restrict__ Pp,
    const unsigned char* __restrict__ XT, const float* __restrict__ x,
    const float* __restrict__ pden, float* __restrict__ out, int Mc, int c0) {
  __shared__ __align__(16) unsigned char sA[16384];
  __shared__ __align__(16) unsigned char sB[16384];
  __shared__ float rden_s[128];

  const int t = threadIdx.x, l = t & 63, w = t >> 6;
  const int wr = w >> 1, wc = w & 1;

  // T1: chunked XCD swizzle (grid (16,8,8), 1024 blocks): XCD c owns b=c;
  // 16 consecutive blocks share one 256 KB XT d-panel.
  const int lin = blockIdx.x + 16 * (blockIdx.y + 8 * blockIdx.z);
  const int wg = (lin & 7) * 128 + (lin >> 3);
  const int q0 = (wg & 15) * 128;
  const int d0 = ((wg >> 4) & 7) * 128;
  const int b = wg >> 7;

  f4 acc[4][4];
  #pragma unroll
  for (int i = 0; i < 4; ++i)
    #pragma unroll
    for (int j = 0; j < 4; ++j) acc[i][j] = (f4)0.0f;

  gemm_mx(sA, sB,
          Pp + ((size_t)b * N_TOK + q0) * (size_t)Mc, (size_t)Mc,
          XT + (((size_t)b * DIM + d0) * (size_t)N_TOK + c0), (size_t)N_TOK,
          Mc / 128, w, l, wr, wc, acc);

  if (FINAL) {
    if (t < 128) {
      const float* pp = pden + ((size_t)b * N_TOK + q0 + t) * 16;
      float s = 0.0f;
      #pragma unroll
      for (int i = 0; i < 16; ++i) s += pp[i];
      rden_s[t] = 1.0f / s;
    }
    __syncthreads();
  }

  #pragma unroll
  for (int j = 0; j < 4; ++j) {
    const int cc = d0 + wc * 64 + j * 16 + (l & 15);
    #pragma unroll
    for (int i = 0; i < 4; ++i)
      #pragma unroll
      for (int e = 0; e < 4; ++e) {
        const int rl = wr * 64 + i * 16 + (l >> 4) * 4 + e;
        const size_t oi = (size_t)(q0 + rl) * (BATCH * DIM) + (size_t)b * DIM + cc;
        float v = acc[i][j][e];
        if (ACC) v += out[oi];
        if (FINAL) v = v * rden_s[rl] + x[oi];
        out[oi] = v;
      }
  }
}

// ---------------- final: out = LN(y) * gamma + beta  (y already = O/den + x) ----------------

__global__ __launch_bounds__(256) void kLN(const float* __restrict__ gamma,
    const float* __restrict__ beta, float* __restrict__ out) {
  __shared__ float sb[8];
  const int r = blockIdx.x;            // r = n*8 + b
  const int t = threadIdx.x;

  const size_t base = (size_t)r * DIM;
  const float4 y4 = *(const float4*)(out + base + t * 4);
  const float y0 = y4.x, y1 = y4.y, y2 = y4.z, y3 = y4.w;

  float s1 = y0 + y1 + y2 + y3;
  float s2 = y0 * y0 + y1 * y1 + y2 * y2 + y3 * y3;
  #pragma unroll
  for (int o = 32; o; o >>= 1) { s1 += __shfl_xor(s1, o); s2 += __shfl_xor(s2, o); }
  if ((t & 63) == 0) { sb[t >> 6] = s1; sb[4 + (t >> 6)] = s2; }
  __syncthreads();
  s1 = sb[0] + sb[1] + sb[2] + sb[3];
  s2 = sb[4] + sb[5] + sb[6] + sb[7];

  const float mean = s1 * (1.0f / DIM);
  const float var = s2 * (1.0f / DIM) - mean * mean;
  const float rstd = rsqrtf(var + 1e-5f);

  const float4 g4 = *(const float4*)(gamma + t * 4);
  const float4 b4 = *(const float4*)(beta + t * 4);
  float4 rr;
  rr.x = (y0 - mean) * rstd * g4.x + b4.x;
  rr.y = (y1 - mean) * rstd * g4.y + b4.y;
  rr.z = (y2 - mean) * rstd * g4.z + b4.z;
  rr.w = (y3 - mean) * rstd * g4.w + b4.w;
  *(float4*)(out + base + t * 4) = rr;
}

// ---------------- launch ----------------

extern "C" void kernel_launch(void* const* d_in, const int* in_sizes, int n_in,
                              void* d_out, int out_size, void* d_ws, size_t ws_size,
                              hipStream_t stream) {
  (void)in_sizes; (void)n_in; (void)out_size;
  const float* x     = (const float*)d_in[0];
  const float* embed = (const float*)d_in[1];
  const float* gamma = (const float*)d_in[2];
  const float* beta  = (const float*)d_in[3];
  float* out = (float*)d_out;

  size_t off = 0;
  char* ws = (char*)d_ws;
  auto take = [&](size_t bytes) { char* p = ws + off; off += bytes; return p; };
  unsigned char* XT  = (unsigned char*)take((size_t)BATCH * DIM * N_TOK);   // 16.8 MB
  unsigned char* xnb = (unsigned char*)take((size_t)BATCH * N_TOK * DIM);   // 16.8 MB
  unsigned char* wnb = (unsigned char*)take((size_t)N_TOK * DIM);           //  2.1 MB
  float* pden = (float*)take((size_t)BATCH * N_TOK * 16 * 4);               //  2.1 MB
  const size_t fixed = off;

  int Mc = 2048;
  while (Mc > 128 && fixed + (size_t)BATCH * N_TOK * Mc > ws_size) Mc >>= 1;
  unsigned char* Pp = (unsigned char*)take((size_t)BATCH * N_TOK * Mc);     // 33.6 MB full

  prep_wn<<<N_TOK, 256, 0, stream>>>(embed, wnb);
  prep_xnorm<<<N_TOK * BATCH, 256, 0, stream>>>(x, xnb);
  prep_xt<<<dim3(N_TOK / 64, DIM / 64, BATCH), 256, 0, stream>>>(x, XT);

  const int nchunk = N_TOK / Mc;
  for (int ci = 0; ci < nchunk; ++ci) {
    const int c0 = ci * Mc;
    kA<<<dim3(16, Mc / 128, BATCH), 256, 0, stream>>>(wnb, xnb, Pp, pden, Mc, c0);
    const bool first = (ci == 0), last = (ci == nchunk - 1);
    if (first && last)
      kB<0, 1><<<dim3(16, 8, BATCH), 256, 0, stream>>>(Pp, XT, x, pden, out, Mc, c0);
    else if (first)
      kB<0, 0><<<dim3(16, 8, BATCH), 256, 0, stream>>>(Pp, XT, x, pden, out, Mc, c0);
    else if (last)
      kB<1, 1><<<dim3(16, 8, BATCH), 256, 0, stream>>>(Pp, XT, x, pden, out, Mc, c0);
    else
      kB<1, 0><<<dim3(16, 8, BATCH), 256, 0, stream>>>(Pp, XT, x, pden, out, Mc, c0);
  }
  kLN<<<N_TOK * BATCH, 256, 0, stream>>>(gamma, beta, out);
}

// Round 8
// 148.401 us; speedup vs baseline: 1.9552x; 1.0892x over previous
//
#include <hip/hip_runtime.h>
#include <hip/hip_bf16.h>

typedef float f4 __attribute__((ext_vector_type(4)));
typedef int i32x4 __attribute__((ext_vector_type(4)));
typedef int i32x8 __attribute__((ext_vector_type(8)));
typedef unsigned char u8x16 __attribute__((ext_vector_type(16)));

#define N_TOK 2048
#define BATCH 8
#define DIM   1024

// ---- fp8 e4m3 (OCP on gfx950) pack helpers ----
static __device__ __forceinline__ unsigned int pk4_fp8(float a, float b, float c, float d) {
  unsigned int v = 0;
  v = __builtin_amdgcn_cvt_pk_fp8_f32(a, b, v, false);
  v = __builtin_amdgcn_cvt_pk_fp8_f32(c, d, v, true);
  return v;
}
static __device__ __forceinline__ unsigned char fp8_1(float a) {
  return (unsigned char)(__builtin_amdgcn_cvt_pk_fp8_f32(a, a, 0, false) & 0xFF);
}
// f32 -> bf16 rne
static __device__ __forceinline__ unsigned short f2bf(float f) {
  unsigned int b = __float_as_uint(f);
  b += 0x7FFFu + ((b >> 16) & 1u);
  return (unsigned short)(b >> 16);
}
static __device__ __forceinline__ float bf2f(unsigned short u) {
  return __uint_as_float(((unsigned int)u) << 16);
}

static __device__ __forceinline__ void gld16(const void* g, void* lds) {
  __builtin_amdgcn_global_load_lds(
      (const __attribute__((address_space(1))) unsigned int*)g,
      (__attribute__((address_space(3))) unsigned int*)lds, 16, 0, 0);
}

// Stage a [128 rows x 128 byte] fp8 tile into 16 KB LDS with 256 threads
// (4 x gld16 each).  Linear LDS dest, XOR-swizzled per-lane global source
// (G21): LDS[row*128 + (g16 ^ ((row&7)<<4))] = G[row][g16] per 16B granule.
static __device__ __forceinline__ void stage_tile(const unsigned char* g, size_t ldb,
                                                  unsigned char* lds, int w, int l) {
  const int rgrp = l >> 3;                       // row within 8-row granule
  const int srcb = (((l & 7) ^ rgrp) << 4);      // swizzled byte offset in row
  #pragma unroll
  for (int gi = 0; gi < 4; ++gi) {
    int rb = (gi * 4 + w) * 8;                   // wave-granule base row
    gld16(g + (size_t)(rb + rgrp) * ldb + srcb, lds + (gi * 4 + w) * 1024);
  }
}

// read one 16x16x128 f8f6f4 fragment: 32 consecutive k-bytes at one row,
// swizzle-aware (two independent 16B granules).  kb is 32B-aligned.
static __device__ __forceinline__ i32x8 fragld32(const unsigned char* lds, int row, int kb) {
  const unsigned char* base = lds + row * 128;
  const int swz = (row & 7) << 4;
  const i32x4 lo = *(const i32x4*)(base + (kb ^ swz));
  const i32x4 hi = *(const i32x4*)(base + ((kb + 16) ^ swz));
  i32x8 r;
  r[0] = lo[0]; r[1] = lo[1]; r[2] = lo[2]; r[3] = lo[3];
  r[4] = hi[0]; r[5] = hi[1]; r[6] = hi[2]; r[7] = hi[3];
  return r;
}

// shared MX-fp8 K-loop (m97/m148 structure: 2-barrier, BK=128, one
// mfma_scale K=128 per (i,j); E8M0 scale 0x7F == 1.0 -> numerics == plain fp8)
static __device__ __forceinline__ void gemm_mx(unsigned char* sA, unsigned char* sB,
    const unsigned char* Ab, size_t lda, const unsigned char* Bb, size_t ldb,
    int nk, int w, int l, int wr, int wc, f4 acc[4][4]) {
  for (int kk = 0; kk < nk; ++kk) {
    stage_tile(Ab + (size_t)kk * 128, lda, sA, w, l);
    stage_tile(Bb + (size_t)kk * 128, ldb, sB, w, l);
    __syncthreads();
    const int kb = (l >> 4) * 32;
    i32x8 af[4], bf[4];
    #pragma unroll
    for (int i = 0; i < 4; ++i)
      af[i] = fragld32(sA, wr * 64 + i * 16 + (l & 15), kb);
    #pragma unroll
    for (int j = 0; j < 4; ++j)
      bf[j] = fragld32(sB, wc * 64 + j * 16 + (l & 15), kb);
    #pragma unroll
    for (int i = 0; i < 4; ++i)
      #pragma unroll
      for (int j = 0; j < 4; ++j)
        acc[i][j] = __builtin_amdgcn_mfma_scale_f32_16x16x128_f8f6f4(
            af[i], bf[j], acc[i][j], 0, 0, 0, 0x7F7F7F7F, 0, 0x7F7F7F7F);
    __syncthreads();
  }
}

// ---------------- prep kernels ----------------

static __device__ __forceinline__ float block_reduce_sum(float v, volatile float* sb, int t) {
  #pragma unroll
  for (int o = 32; o; o >>= 1) v += __shfl_xor(v, o);
  if ((t & 63) == 0) sb[t >> 6] = v;
  __syncthreads();
  float r = sb[0] + sb[1] + sb[2] + sb[3];
  __syncthreads();
  return r;
}

// embed -> RAW fp8 wn + winv[n]  (one block per row)
__global__ __launch_bounds__(256) void prep_wn(const float* __restrict__ e,
                                               unsigned char* __restrict__ wn,
                                               float* __restrict__ winv) {
  __shared__ float sb[4];
  const int n = blockIdx.x, t = threadIdx.x;
  const float4 v = *(const float4*)(e + (size_t)n * DIM + t * 4);
  float ss = v.x * v.x + v.y * v.y + v.z * v.z + v.w * v.w;
  ss = block_reduce_sum(ss, sb, t);
  if (t == 0) winv[n] = rsqrtf(fmaxf(ss, 1e-24f));
  *(unsigned int*)(wn + (size_t)n * DIM + t * 4) = pk4_fp8(v.x, v.y, v.z, v.w);
}

// Fused x pass (reads x ONCE): raw fp8 in BOTH layouts + per-row ss partials.
//   xr8[b][m][d]  (kA B-operand), XT[b][d][m] (kB B-operand),
//   sspart[b][m][16] deterministic per-(64d)-tile partial sums of x^2.
__global__ __launch_bounds__(256) void prep_x(const float* __restrict__ x,
    unsigned char* __restrict__ xr8, unsigned char* __restrict__ XT,
    float* __restrict__ sspart) {
  __shared__ unsigned char tile[64][72];
  const int t = threadIdx.x;
  const int m0 = blockIdx.x * 64, d0 = blockIdx.y * 64, b = blockIdx.z;
  {
    const int ml = t >> 2, dc = (t & 3) * 16;
    const float* row = x + ((size_t)(m0 + ml) * BATCH + b) * DIM + d0 + dc;
    union { unsigned int u[4]; u8x16 v; } pk;
    float ssp = 0.0f;
    #pragma unroll
    for (int i = 0; i < 4; ++i) {
      float4 v = *(const float4*)(row + i * 4);
      ssp += v.x * v.x + v.y * v.y + v.z * v.z + v.w * v.w;
      pk.u[i] = pk4_fp8(v.x, v.y, v.z, v.w);
    }
    *(u8x16*)(xr8 + ((size_t)b * N_TOK + m0 + ml) * DIM + d0 + dc) = pk.v;
    *(u8x16*)&tile[ml][dc] = pk.v;
    ssp += __shfl_xor(ssp, 1);
    ssp += __shfl_xor(ssp, 2);
    if ((t & 3) == 0)
      sspart[((size_t)b * N_TOK + m0 + ml) * 16 + (d0 >> 6)] = ssp;
  }
  __syncthreads();
  {
    const int dl = t >> 2, mc = (t & 3) * 16;
    union { unsigned char c[16]; u8x16 v; } o;
    #pragma unroll
    for (int ii = 0; ii < 16; ++ii) o.c[ii] = tile[mc + ii][dl];
    *(u8x16*)(XT + ((size_t)b * DIM + d0 + dl) * (size_t)N_TOK + m0 + mc) = o.v;
  }
}

// sspart -> xinv[b][m]
__global__ __launch_bounds__(256) void prep_xinv(const float* __restrict__ sspart,
                                                 float* __restrict__ xinv) {
  const int i = blockIdx.x * 256 + threadIdx.x;   // b*N_TOK + m
  const float* p = sspart + (size_t)i * 16;
  float s = 0.0f;
  #pragma unroll
  for (int k = 0; k < 16; ++k) s += p[k];
  xinv[i] = rsqrtf(fmaxf(s, 1e-24f));
}

// ---------------- GEMM A: Sraw = wn . xr8^T ; P = exp(Sraw*winv*xinv) ; denominators ----------------

__global__ __launch_bounds__(256, 3) void kA(
    const unsigned char* __restrict__ wn, const unsigned char* __restrict__ xr8,
    const float* __restrict__ winv, const float* __restrict__ xinv,
    unsigned char* __restrict__ Pp, float* __restrict__ pden, int Mc, int c0) {
  __shared__ __align__(16) unsigned char sA[16384];
  __shared__ __align__(16) unsigned char sB[16384];
  __shared__ float pd[128][2];
  __shared__ float winv_s[128], xinv_s[128];

  const int t = threadIdx.x, l = t & 63, w = t >> 6;
  const int wr = w >> 1, wc = w & 1;

  // T1: chunked XCD swizzle (grid (16, Mc/128, 8); nwg % 8 == 0 -> bijective).
  const int gy = Mc >> 7;
  const int nwg = 16 * gy * 8;
  const int lin = blockIdx.x + 16 * (blockIdx.y + gy * blockIdx.z);
  const int wg = (lin & 7) * (nwg >> 3) + (lin >> 3);
  const int xx = wg & 15, yy = (wg >> 4) % gy, zz = (wg >> 4) / gy;

  const int q0 = xx * 128;
  const int m0l = yy * 128;
  const int b = zz;
  const int m0g = c0 + m0l;

  if (t < 128) winv_s[t] = winv[q0 + t];
  else         xinv_s[t - 128] = xinv[b * N_TOK + m0g + (t - 128)];

  f4 acc[4][4];
  #pragma unroll
  for (int i = 0; i < 4; ++i)
    #pragma unroll
    for (int j = 0; j < 4; ++j) acc[i][j] = (f4)0.0f;

  gemm_mx(sA, sB,
          wn + (size_t)q0 * DIM, DIM,
          xr8 + ((size_t)b * N_TOK + m0g) * DIM, DIM,
          DIM / 128, w, l, wr, wc, acc);

  // epilogue: S = Sraw*winv*xinv in [-1,1]; P = exp(S) fp8 + row sums
  float ra[4][4];
  #pragma unroll
  for (int i = 0; i < 4; ++i)
    #pragma unroll
    for (int e = 0; e < 4; ++e) ra[i][e] = 0.0f;

  #pragma unroll
  for (int j = 0; j < 4; ++j) {
    const int cl = wc * 64 + j * 16 + (l & 15);  // local m col
    const float xv = xinv_s[cl];
    #pragma unroll
    for (int i = 0; i < 4; ++i)
      #pragma unroll
      for (int e = 0; e < 4; ++e) {
        const int row = wr * 64 + i * 16 + (l >> 4) * 4 + e;  // local q
        const float p = __expf(acc[i][j][e] * winv_s[row] * xv);
        ra[i][e] += p;
        Pp[((size_t)b * N_TOK + q0 + row) * (size_t)Mc + m0l + cl] = fp8_1(p);
      }
  }
  #pragma unroll
  for (int i = 0; i < 4; ++i)
    #pragma unroll
    for (int e = 0; e < 4; ++e) {
      float s = ra[i][e];
      s += __shfl_xor(s, 1); s += __shfl_xor(s, 2);
      s += __shfl_xor(s, 4); s += __shfl_xor(s, 8);
      if ((l & 15) == 0) pd[wr * 64 + i * 16 + (l >> 4) * 4 + e][wc] = s;
    }
  __syncthreads();
  if (t < 128)
    pden[((size_t)b * N_TOK + q0 + t) * 16 + (c0 >> 7) + yy] = pd[t][0] + pd[t][1];
}

// ---------------- GEMM B: O += P . V ; final applies 1/den and +x (y as bf16 if YBF) ----------------

template <int ACC, int FINAL, int YBF>
__global__ __launch_bounds__(256, 3) void kB(const unsigned char* __restrict__ Pp,
    const unsigned char* __restrict__ XT, const float* __restrict__ x,
    const float* __restrict__ pden, float* __restrict__ out,
    unsigned short* __restrict__ ybf, int Mc, int c0) {
  __shared__ __align__(16) unsigned char sA[16384];
  __shared__ __align__(16) unsigned char sB[16384];
  __shared__ float rden_s[128];

  const int t = threadIdx.x, l = t & 63, w = t >> 6;
  const int wr = w >> 1, wc = w & 1;

  // T1: chunked XCD swizzle (grid (16,8,8), 1024 blocks): XCD c owns b=c.
  const int lin = blockIdx.x + 16 * (blockIdx.y + 8 * blockIdx.z);
  const int wg = (lin & 7) * 128 + (lin >> 3);
  const int q0 = (wg & 15) * 128;
  const int d0 = ((wg >> 4) & 7) * 128;
  const int b = wg >> 7;

  f4 acc[4][4];
  #pragma unroll
  for (int i = 0; i < 4; ++i)
    #pragma unroll
    for (int j = 0; j < 4; ++j) acc[i][j] = (f4)0.0f;

  gemm_mx(sA, sB,
          Pp + ((size_t)b * N_TOK + q0) * (size_t)Mc, (size_t)Mc,
          XT + (((size_t)b * DIM + d0) * (size_t)N_TOK + c0), (size_t)N_TOK,
          Mc / 128, w, l, wr, wc, acc);

  if (FINAL) {
    if (t < 128) {
      const float* pp = pden + ((size_t)b * N_TOK + q0 + t) * 16;
      float s = 0.0f;
      #pragma unroll
      for (int i = 0; i < 16; ++i) s += pp[i];
      rden_s[t] = 1.0f / s;
    }
    __syncthreads();
  }

  #pragma unroll
  for (int j = 0; j < 4; ++j) {
    const int cc = d0 + wc * 64 + j * 16 + (l & 15);
    #pragma unroll
    for (int i = 0; i < 4; ++i)
      #pragma unroll
      for (int e = 0; e < 4; ++e) {
        const int rl = wr * 64 + i * 16 + (l >> 4) * 4 + e;
        const size_t oi = (size_t)(q0 + rl) * (BATCH * DIM) + (size_t)b * DIM + cc;
        float v = acc[i][j][e];
        if (ACC) v += out[oi];
        if (FINAL) {
          v = v * rden_s[rl] + x[oi];
          if (YBF) { ybf[oi] = f2bf(v); continue; }
        }
        out[oi] = v;
      }
  }
}

// ---------------- final: out = LN(y) * gamma + beta  (y already = O/den + x) ----------------

template <int YBF>
__global__ __launch_bounds__(256) void kLN(const float* __restrict__ gamma,
    const float* __restrict__ beta, const unsigned short* __restrict__ ybf,
    float* __restrict__ out) {
  __shared__ float sb[8];
  const int r = blockIdx.x;            // r = n*8 + b
  const int t = threadIdx.x;

  const size_t base = (size_t)r * DIM;
  float y0, y1, y2, y3;
  if (YBF) {
    const ushort4 u = *(const ushort4*)(ybf + base + t * 4);
    y0 = bf2f(u.x); y1 = bf2f(u.y); y2 = bf2f(u.z); y3 = bf2f(u.w);
  } else {
    const float4 y4 = *(const float4*)(out + base + t * 4);
    y0 = y4.x; y1 = y4.y; y2 = y4.z; y3 = y4.w;
  }

  float s1 = y0 + y1 + y2 + y3;
  float s2 = y0 * y0 + y1 * y1 + y2 * y2 + y3 * y3;
  #pragma unroll
  for (int o = 32; o; o >>= 1) { s1 += __shfl_xor(s1, o); s2 += __shfl_xor(s2, o); }
  if ((t & 63) == 0) { sb[t >> 6] = s1; sb[4 + (t >> 6)] = s2; }
  __syncthreads();
  s1 = sb[0] + sb[1] + sb[2] + sb[3];
  s2 = sb[4] + sb[5] + sb[6] + sb[7];

  const float mean = s1 * (1.0f / DIM);
  const float var = s2 * (1.0f / DIM) - mean * mean;
  const float rstd = rsqrtf(var + 1e-5f);

  const float4 g4 = *(const float4*)(gamma + t * 4);
  const float4 b4 = *(const float4*)(beta + t * 4);
  float4 rr;
  rr.x = (y0 - mean) * rstd * g4.x + b4.x;
  rr.y = (y1 - mean) * rstd * g4.y + b4.y;
  rr.z = (y2 - mean) * rstd * g4.z + b4.z;
  rr.w = (y3 - mean) * rstd * g4.w + b4.w;
  *(float4*)(out + base + t * 4) = rr;
}

// ---------------- launch ----------------

extern "C" void kernel_launch(void* const* d_in, const int* in_sizes, int n_in,
                              void* d_out, int out_size, void* d_ws, size_t ws_size,
                              hipStream_t stream) {
  (void)in_sizes; (void)n_in; (void)out_size;
  const float* x     = (const float*)d_in[0];
  const float* embed = (const float*)d_in[1];
  const float* gamma = (const float*)d_in[2];
  const float* beta  = (const float*)d_in[3];
  float* out = (float*)d_out;

  size_t off = 0;
  char* ws = (char*)d_ws;
  auto take = [&](size_t bytes) { char* p = ws + off; off += bytes; return p; };
  unsigned char* XT   = (unsigned char*)take((size_t)BATCH * DIM * N_TOK);     // 16.8 MB
  unsigned char* xr8  = (unsigned char*)take((size_t)BATCH * N_TOK * DIM);     // 16.8 MB
  unsigned char* wn8  = (unsigned char*)take((size_t)N_TOK * DIM);             //  2.1 MB
  float* winv   = (float*)take((size_t)N_TOK * 4);                             //  8 KB
  float* sspart = (float*)take((size_t)BATCH * N_TOK * 16 * 4);                //  2.1 MB
  float* xinv   = (float*)take((size_t)BATCH * N_TOK * 4);                     // 64 KB
  float* pden   = (float*)take((size_t)BATCH * N_TOK * 16 * 4);                //  2.1 MB
  const size_t fixed = off;

  int Mc = 2048;
  while (Mc > 128 && fixed + (size_t)BATCH * N_TOK * Mc > ws_size) Mc >>= 1;
  unsigned char* Pp = (unsigned char*)take((size_t)BATCH * N_TOK * Mc);        // 33.6 MB full

  const size_t ybf_bytes = (size_t)N_TOK * BATCH * DIM * 2;                    // 33.6 MB
  const int use_ybf = (off + ybf_bytes <= ws_size) ? 1 : 0;
  unsigned short* ybf = use_ybf ? (unsigned short*)take(ybf_bytes) : (unsigned short*)out;

  prep_wn<<<N_TOK, 256, 0, stream>>>(embed, wn8, winv);
  prep_x<<<dim3(N_TOK / 64, DIM / 64, BATCH), 256, 0, stream>>>(x, xr8, XT, sspart);
  prep_xinv<<<(N_TOK * BATCH) / 256, 256, 0, stream>>>(sspart, xinv);

  const int nchunk = N_TOK / Mc;
  for (int ci = 0; ci < nchunk; ++ci) {
    const int c0 = ci * Mc;
    kA<<<dim3(16, Mc / 128, BATCH), 256, 0, stream>>>(wn8, xr8, winv, xinv, Pp, pden, Mc, c0);
    const bool first = (ci == 0), last = (ci == nchunk - 1);
    const dim3 gB(16, 8, BATCH);
    if (last) {
      if (use_ybf) {
        if (first) kB<0, 1, 1><<<gB, 256, 0, stream>>>(Pp, XT, x, pden, out, ybf, Mc, c0);
        else       kB<1, 1, 1><<<gB, 256, 0, stream>>>(Pp, XT, x, pden, out, ybf, Mc, c0);
      } else {
        if (first) kB<0, 1, 0><<<gB, 256, 0, stream>>>(Pp, XT, x, pden, out, ybf, Mc, c0);
        else       kB<1, 1, 0><<<gB, 256, 0, stream>>>(Pp, XT, x, pden, out, ybf, Mc, c0);
      }
    } else {
      if (first) kB<0, 0, 0><<<gB, 256, 0, stream>>>(Pp, XT, x, pden, out, ybf, Mc, c0);
      else       kB<1, 0, 0><<<gB, 256, 0, stream>>>(Pp, XT, x, pden, out, ybf, Mc, c0);
    }
  }
  if (use_ybf) kLN<1><<<N_TOK * BATCH, 256, 0, stream>>>(gamma, beta, ybf, out);
  else         kLN<0><<<N_TOK * BATCH, 256, 0, stream>>>(gamma, beta, ybf, out);
}